// Round 16
// baseline (141.461 us; speedup 1.0000x reference)
//
#include <hip/hip_runtime.h>
#include <hip/hip_fp16.h>

#define THREADS 256
#define BKT_SHIFT 9          // 512 nodes per bucket
#define BKT_NODES 512
#define BKT_CAP 12288        // max edges per bucket (mean ~8192 for E=1.6M)
#define RPW 4                // rows per wave in k_g2l12

typedef _Float16 h2 __attribute__((ext_vector_type(2)));

__device__ inline h2 u2h(unsigned u) { union { unsigned u; h2 h; } c; c.u = u; return c.h; }
__device__ inline unsigned h2u(h2 h) { union { unsigned u; h2 h; } c; c.h = h; return c.u; }
__device__ inline float fdot2f(h2 a, h2 b, float c) { return __builtin_amdgcn_fdot2(a, b, c, false); }
__device__ inline float rdlane_f(float v, int l) {
    return __uint_as_float((unsigned)__builtin_amdgcn_readlane(__float_as_uint(v), l));
}

// zero bucket counters + pack W2 into fp16 lane-major table P[j*32+m] = (W2[2m][j], W2[2m+1][j])
__global__ void k_prep(int* __restrict__ bucket_cnt, const float* __restrict__ W2,
                       unsigned* __restrict__ w2pk) {
    int t = threadIdx.x;
    if (t < 256) bucket_cnt[t] = 0;
    for (int idx = t; idx < 2048; idx += THREADS) {
        int j = idx >> 5, m = idx & 31;
        h2 w;
        w[0] = (_Float16)W2[(2 * m) * 64 + j];
        w[1] = (_Float16)W2[(2 * m + 1) * 64 + j];
        w2pk[idx] = h2u(w);
    }
}

// ---------- Pass A: bin edges into coarse buckets (dst>>9), packed src|dlow<<17 ----------
__global__ void k_binA(const int* __restrict__ src, const int* __restrict__ dst,
                       int* __restrict__ bucket_cnt, unsigned int* __restrict__ binned,
                       int E, int NB) {
    __shared__ int hist[256];
    __shared__ int cur[256];
    int t = threadIdx.x;
    if (t < NB) hist[t] = 0;
    __syncthreads();
    int chunk = (E + gridDim.x - 1) / gridDim.x;
    int e0 = blockIdx.x * chunk;
    int e1 = min(E, e0 + chunk);
    for (int e = e0 + t; e < e1; e += THREADS) atomicAdd(&hist[dst[e] >> BKT_SHIFT], 1);
    __syncthreads();
    if (t < NB) {
        int c = hist[t];
        cur[t] = c ? atomicAdd(&bucket_cnt[t], c) : 0;
    }
    __syncthreads();
    for (int e = e0 + t; e < e1; e += THREADS) {
        int d = dst[e];
        int b = d >> BKT_SHIFT;
        int pos = atomicAdd(&cur[b], 1);
        if (pos < BKT_CAP)
            binned[(size_t)b * BKT_CAP + pos] =
                (unsigned int)src[e] | ((unsigned int)(d & (BKT_NODES - 1)) << 17);
    }
}

// ---------- Pass B: per-bucket prefix (in-block) + LDS hist+scan -> row_ptr, dinv, xs, esrc ----------
// esrc entries are PRE-SCALED to fp16-row byte offsets (node << 7)
__global__ void k_binB(const unsigned int* __restrict__ binned, const int* __restrict__ bucket_cnt,
                       const float2* __restrict__ x,
                       int* __restrict__ row_ptr, float* __restrict__ dinv,
                       float2* __restrict__ xs, int* __restrict__ esrc, int N, int E) {
    __shared__ int bc[256];
    __shared__ int h[BKT_NODES], sc[BKT_NODES], cur[BKT_NODES];
    int b = blockIdx.x, t = threadIdx.x;   // blockDim = 512
    int NB = gridDim.x;
    // in-block exclusive prefix of bucket counts -> base
    if (t < 256) bc[t] = (t < NB) ? bucket_cnt[t] : 0;
    __syncthreads();
    for (int off = 1; off < 256; off <<= 1) {
        int u = (t >= off && t < 256) ? bc[t - off] : 0;
        __syncthreads();
        if (t < 256) bc[t] += u;
        __syncthreads();
    }
    int base = (b > 0) ? bc[b - 1] : 0;
    if (b == 0 && t == 0) row_ptr[N] = E;
    int cntb = min(bucket_cnt[b], BKT_CAP);
    h[t] = 0;
    __syncthreads();
    const unsigned int* bp = binned + (size_t)b * BKT_CAP;
    for (int e = t; e < cntb; e += BKT_NODES) atomicAdd(&h[bp[e] >> 17], 1);
    __syncthreads();
    sc[t] = h[t];
    __syncthreads();
    for (int off = 1; off < BKT_NODES; off <<= 1) {
        int u = (t >= off) ? sc[t - off] : 0;
        __syncthreads();
        sc[t] += u;
        __syncthreads();
    }
    int node = b * BKT_NODES + t;
    if (node < N) {
        int excl = sc[t] - h[t];
        row_ptr[node] = base + excl;
        cur[t] = excl;
        float dv = rsqrtf((float)(h[t] + 1));
        dinv[node] = dv;
        float2 v = x[node];
        xs[node] = make_float2(v.x * dv, v.y * dv);
    }
    __syncthreads();
    for (int e = t; e < cntb; e += BKT_NODES) {
        unsigned int p = bp[e];
        int pos = atomicAdd(&cur[p >> 17], 1);
        esrc[base + pos] = (int)((p & 0x1FFFFu) << 7);
    }
}

// ---------- fused: 2-dim gather + layer-1 transform + layer-2 transform ----------
// 4 rows per wave in 16-lane groups for the gather (4-round shared reduce);
// matvec: lane j holds fp16 W2 column j (32 half2, loaded via 8 uint4 from packed table),
// two rows interleaved; h-pairs broadcast via v_readlane (no LDS).
__global__ void k_g2l12(const int* __restrict__ row_ptr, const int* __restrict__ esrc,
                        const float* __restrict__ dinv, const float2* __restrict__ xs,
                        const float* __restrict__ W1, const float* __restrict__ b1,
                        const unsigned* __restrict__ w2pk, __half* __restrict__ A, int n) {
    int tid = threadIdx.x;
    int j = tid & 63;
    int gw = blockIdx.x * (THREADS / 64) + (tid >> 6);   // global wave id
    int row0 = gw * RPW;
    if (row0 >= n) return;

    h2 w2p[32];
    {
        const uint4* Wp = (const uint4*)(w2pk + j * 32);
#pragma unroll
        for (int g4 = 0; g4 < 8; ++g4) {
            uint4 q = Wp[g4];
            w2p[4 * g4 + 0] = u2h(q.x);
            w2p[4 * g4 + 1] = u2h(q.y);
            w2p[4 * g4 + 2] = u2h(q.z);
            w2p[4 * g4 + 3] = u2h(q.w);
        }
    }
    // lane m<32 owns h-columns 2m, 2m+1 (lanes >=32 duplicate lane 0's, unused)
    int jj = (j < 32) ? j : 0;
    float w1xa = W1[2 * jj],     w1ya = W1[64 + 2 * jj],     b1a = b1[2 * jj];
    float w1xb = W1[2 * jj + 1], w1yb = W1[64 + 2 * jj + 1], b1b = b1[2 * jj + 1];

    int r = j >> 4;          // row slot 0..3
    int u = j & 15;          // edge lane within group

    {
        int rowg = row0;
        int myrow = rowg + r;
        float ax = 0.0f, ay = 0.0f;
        if (myrow < n) {
            int e0 = row_ptr[myrow], e1 = row_ptr[myrow + 1];
            for (int e = e0 + u; e < e1; e += 16) {
                float2 v = xs[(unsigned)esrc[e] >> 7];
                ax += v.x;
                ay += v.y;
            }
        }
#pragma unroll
        for (int m = 1; m < 16; m <<= 1) {
            ax += __shfl_xor(ax, m, 64);
            ay += __shfl_xor(ay, m, 64);
        }
#pragma unroll
        for (int pr = 0; pr < 2; ++pr) {
            int rowA = rowg + 2 * pr;
            int rowB = rowA + 1;
            int rA = min(rowA, n - 1), rB = min(rowB, n - 1);
            float sxA = rdlane_f(ax, 32 * pr),      syA = rdlane_f(ay, 32 * pr);
            float sxB = rdlane_f(ax, 32 * pr + 16), syB = rdlane_f(ay, 32 * pr + 16);
            float2 ownA = xs[rA], ownB = xs[rB];
            float dvA = dinv[rA], dvB = dinv[rB];
            float gxA = (sxA + ownA.x) * dvA, gyA = (syA + ownA.y) * dvA;
            float gxB = (sxB + ownB.x) * dvB, gyB = (syB + ownB.y) * dvB;
            float haA = fmaxf(gxA * w1xa + gyA * w1ya + b1a, 0.0f);
            float hbA = fmaxf(gxA * w1xb + gyA * w1yb + b1b, 0.0f);
            float haB = fmaxf(gxB * w1xa + gyB * w1ya + b1a, 0.0f);
            float hbB = fmaxf(gxB * w1xb + gyB * w1yb + b1b, 0.0f);
            h2 pkA, pkB;
            pkA[0] = (_Float16)haA; pkA[1] = (_Float16)hbA;
            pkB[0] = (_Float16)haB; pkB[1] = (_Float16)hbB;
            unsigned hpuA = h2u(pkA), hpuB = h2u(pkB);
            float a0 = 0.f, a1 = 0.f, a2 = 0.f, a3 = 0.f;
            float c0 = 0.f, c1 = 0.f, c2 = 0.f, c3 = 0.f;
#pragma unroll
            for (int m = 0; m < 32; m += 4) {
                unsigned pA0 = (unsigned)__builtin_amdgcn_readlane((int)hpuA, m);
                unsigned pA1 = (unsigned)__builtin_amdgcn_readlane((int)hpuA, m + 1);
                unsigned pA2 = (unsigned)__builtin_amdgcn_readlane((int)hpuA, m + 2);
                unsigned pA3 = (unsigned)__builtin_amdgcn_readlane((int)hpuA, m + 3);
                unsigned pB0 = (unsigned)__builtin_amdgcn_readlane((int)hpuB, m);
                unsigned pB1 = (unsigned)__builtin_amdgcn_readlane((int)hpuB, m + 1);
                unsigned pB2 = (unsigned)__builtin_amdgcn_readlane((int)hpuB, m + 2);
                unsigned pB3 = (unsigned)__builtin_amdgcn_readlane((int)hpuB, m + 3);
                a0 = fdot2f(u2h(pA0), w2p[m], a0);
                a1 = fdot2f(u2h(pA1), w2p[m + 1], a1);
                a2 = fdot2f(u2h(pA2), w2p[m + 2], a2);
                a3 = fdot2f(u2h(pA3), w2p[m + 3], a3);
                c0 = fdot2f(u2h(pB0), w2p[m], c0);
                c1 = fdot2f(u2h(pB1), w2p[m + 1], c1);
                c2 = fdot2f(u2h(pB2), w2p[m + 2], c2);
                c3 = fdot2f(u2h(pB3), w2p[m + 3], c3);
            }
            float rAA = ((a0 + a1) + (a2 + a3)) * dvA;
            float rBB = ((c0 + c1) + (c2 + c3)) * dvB;
            float rAp = __shfl_xor(rAA, 1, 64);
            float rBp = __shfl_xor(rBB, 1, 64);
            if ((j & 1) == 0) {
                if (rowA < n) *(__half2*)&A[(size_t)rowA * 64 + j] = __floats2half2_rn(rAA, rAp);
                if (rowB < n) *(__half2*)&A[(size_t)rowB * 64 + j] = __floats2half2_rn(rBB, rBp);
            }
        }
    }
}

// unpack-accumulate 8 halves (one uint4) with v_dot2_f32_f16 (1 VALU op per dim)
__device__ inline void add8d(float a[8], uint4 u, h2 c10, h2 c01) {
    h2 p0 = u2h(u.x), p1 = u2h(u.y), p2 = u2h(u.z), p3 = u2h(u.w);
    a[0] = fdot2f(p0, c10, a[0]); a[1] = fdot2f(p0, c01, a[1]);
    a[2] = fdot2f(p1, c10, a[2]); a[3] = fdot2f(p1, c01, a[3]);
    a[4] = fdot2f(p2, c10, a[4]); a[5] = fdot2f(p2, c01, a[5]);
    a[6] = fdot2f(p3, c10, a[6]); a[7] = fdot2f(p3, c01, a[7]);
}

// ---------- fused: 64-dim fp16 aggregation + bias + relu + layer-3 transform ----------
// 4 nodes per wave; 16-lane group per node = 2 edge-slots x 8 dim-octets;
// each lane loads 16B = 8 halves; esrc holds row byte-offsets
__global__ void k_gather64f(const int* __restrict__ row_ptr, const int* __restrict__ esrc,
                            const float* __restrict__ dinv, const __half* __restrict__ tt,
                            const float* __restrict__ b2, const float* __restrict__ W3,
                            float* __restrict__ tt3, int n) {
    int tid = blockIdx.x * blockDim.x + threadIdx.x;
    int i = tid >> 4;               // node per 16-lane group
    if (i >= n) return;
    int lane = tid & 15;
    int q = lane >> 3;              // edge slot 0..1
    int c = lane & 7;               // dim octet 0..7 (dims 8c..8c+7)
    h2 c10, c01;
    c10[0] = (_Float16)1.0f; c10[1] = (_Float16)0.0f;
    c01[0] = (_Float16)0.0f; c01[1] = (_Float16)1.0f;
    const char* ttb = (const char*)tt + c * 16;
    float a[8];
#pragma unroll
    for (int d = 0; d < 8; ++d) a[d] = 0.0f;
    if (q == 0) add8d(a, *(const uint4*)(ttb + (size_t)i * 128), c10, c01);
    int e0 = row_ptr[i], e1 = row_ptr[i + 1];
    int e = e0 + q;
    for (; e + 6 < e1; e += 8) {
        unsigned o0 = (unsigned)esrc[e],     o1 = (unsigned)esrc[e + 2];
        unsigned o2 = (unsigned)esrc[e + 4], o3 = (unsigned)esrc[e + 6];
        uint4 u0 = *(const uint4*)(ttb + o0);
        uint4 u1 = *(const uint4*)(ttb + o1);
        uint4 u2 = *(const uint4*)(ttb + o2);
        uint4 u3 = *(const uint4*)(ttb + o3);
        add8d(a, u0, c10, c01);
        add8d(a, u1, c10, c01);
        add8d(a, u2, c10, c01);
        add8d(a, u3, c10, c01);
    }
    for (; e < e1; e += 2) {
        uint4 u = *(const uint4*)(ttb + (unsigned)esrc[e]);
        add8d(a, u, c10, c01);
    }
    // reduce across the 2 edge slots (lanes differing by 8)
#pragma unroll
    for (int d = 0; d < 8; ++d) a[d] += __shfl_xor(a[d], 8, 64);
    if (q == 0) {
        float dv = dinv[i];
        const float4 blo = *(const float4*)&b2[c * 8];
        const float4 bhi = *(const float4*)&b2[c * 8 + 4];
        const float4 wlo = *(const float4*)&W3[c * 8];
        const float4 whi = *(const float4*)&W3[c * 8 + 4];
        float p = fmaxf(a[0] * dv + blo.x, 0.0f) * wlo.x
                + fmaxf(a[1] * dv + blo.y, 0.0f) * wlo.y
                + fmaxf(a[2] * dv + blo.z, 0.0f) * wlo.z
                + fmaxf(a[3] * dv + blo.w, 0.0f) * wlo.w
                + fmaxf(a[4] * dv + bhi.x, 0.0f) * whi.x
                + fmaxf(a[5] * dv + bhi.y, 0.0f) * whi.y
                + fmaxf(a[6] * dv + bhi.z, 0.0f) * whi.z
                + fmaxf(a[7] * dv + bhi.w, 0.0f) * whi.w;
        // reduce across the 8 octet lanes
        p += __shfl_xor(p, 1, 64);
        p += __shfl_xor(p, 2, 64);
        p += __shfl_xor(p, 4, 64);
        if (c == 0) tt3[i] = p * dv;
    }
}

// out[i] = dinv[i]*(tt3[i] + sum tt3[esrc>>7]) + b3
__global__ void k_gather1(const int* __restrict__ row_ptr, const int* __restrict__ esrc,
                          const float* __restrict__ dinv, const float* __restrict__ tt3,
                          const float* __restrict__ b3, float* __restrict__ out, int n) {
    int i = blockIdx.x * blockDim.x + threadIdx.x;
    if (i >= n) return;
    float acc = tt3[i];
    int e = row_ptr[i], e1 = row_ptr[i + 1];
    for (; e + 4 <= e1; e += 4) {
        acc += tt3[(unsigned)esrc[e] >> 7] + tt3[(unsigned)esrc[e + 1] >> 7]
             + tt3[(unsigned)esrc[e + 2] >> 7] + tt3[(unsigned)esrc[e + 3] >> 7];
    }
    for (; e < e1; ++e) acc += tt3[(unsigned)esrc[e] >> 7];
    out[i] = acc * dinv[i] + b3[0];
}

extern "C" void kernel_launch(void* const* d_in, const int* in_sizes, int n_in,
                              void* d_out, int out_size, void* d_ws, size_t ws_size,
                              hipStream_t stream) {
    const float* x  = (const float*)d_in[0];
    const int*   ei = (const int*)d_in[1];
    const float* W1 = (const float*)d_in[2];
    const float* b1 = (const float*)d_in[3];
    const float* W2 = (const float*)d_in[4];
    const float* b2 = (const float*)d_in[5];
    const float* W3 = (const float*)d_in[6];
    const float* b3 = (const float*)d_in[7];
    float* out = (float*)d_out;

    const int N = in_sizes[0] / 2;
    const int E = in_sizes[1] / 2;
    const int* src = ei;
    const int* dst = ei + E;
    const int NB = (N + BKT_NODES - 1) >> BKT_SHIFT;

    char* ws = (char*)d_ws;
    float* dinv = (float*)ws;                       // N
    size_t off = ((size_t)N * sizeof(float) + 255) & ~(size_t)255;
    float* Af = (float*)(ws + off);                 // N*64 floats reserved (binned aliases)
    __half* A = (__half*)Af;                        // used as N*64 halves
    float* tt3 = Af + (size_t)N * 64;               // N
    float2* xs = (float2*)(tt3 + N);                // N float2
    int* bucket_cnt = (int*)(xs + N);               // 256
    unsigned* w2pk = (unsigned*)(bucket_cnt + 256); // 2048 (packed fp16 W2)
    int* row_ptr = (int*)(w2pk + 2048);             // N+1
    int* esrc = row_ptr + N + 2;                    // E
    unsigned int* binned = (unsigned int*)Af;       // NB*BKT_CAP u32

    dim3 blk(THREADS);
    dim3 gN((N + THREADS - 1) / THREADS);
    dim3 gN16((int)(((long long)N * 16 + THREADS - 1) / THREADS));

    // prep (zero counters + pack W2) and CSR build (bucket sort)
    k_prep<<<dim3(1), blk, 0, stream>>>(bucket_cnt, W2, w2pk);
    k_binA<<<dim3(1024), blk, 0, stream>>>(src, dst, bucket_cnt, binned, E, NB);
    k_binB<<<dim3(NB), dim3(BKT_NODES), 0, stream>>>(binned, bucket_cnt,
                                                     (const float2*)x, row_ptr, dinv, xs, esrc,
                                                     N, E);

    // layer 1 propagate (2-dim) + transforms 1&2 fused (16-lane gather, 2-row matvec)
    {
        int waves = (N + RPW - 1) / RPW;
        int blocks = (waves + (THREADS / 64) - 1) / (THREADS / 64);
        k_g2l12<<<dim3(blocks), blk, 0, stream>>>(row_ptr, esrc, dinv, xs, W1, b1, w2pk, A, N);
    }

    // layer 2 aggregation + bias/relu + layer-3 transform fused (fp16 table, dot2)
    k_gather64f<<<gN16, blk, 0, stream>>>(row_ptr, esrc, dinv, A, b2, W3, tt3, N);

    // layer 3 propagate
    k_gather1<<<gN, blk, 0, stream>>>(row_ptr, esrc, dinv, tt3, b3, out, N);
}

// Round 17
// 124.836 us; speedup vs baseline: 1.1332x; 1.1332x over previous
//
#include <hip/hip_runtime.h>
#include <hip/hip_fp16.h>

#define THREADS 256
#define BKT_SHIFT 9          // 512 nodes per bucket
#define BKT_NODES 512
#define BKT_CAP 12288        // max edges per bucket (mean ~8192 for E=1.6M)
#define RPW 8                // rows per wave in k_g2l12

typedef _Float16 h2 __attribute__((ext_vector_type(2)));

__device__ inline h2 u2h(unsigned u) { union { unsigned u; h2 h; } c; c.u = u; return c.h; }
__device__ inline unsigned h2u(h2 h) { union { unsigned u; h2 h; } c; c.h = h; return c.u; }
__device__ inline float fdot2f(h2 a, h2 b, float c) { return __builtin_amdgcn_fdot2(a, b, c, false); }
__device__ inline float rdlane_f(float v, int l) {
    return __uint_as_float((unsigned)__builtin_amdgcn_readlane(__float_as_uint(v), l));
}

// zero the bucket counters
__global__ void k_zero_int(int* __restrict__ p, int n) {
    int i = threadIdx.x;
    if (i < n) p[i] = 0;
}

// ---------- Pass A: bin edges into coarse buckets (dst>>9), packed src|dlow<<17 ----------
__global__ void k_binA(const int* __restrict__ src, const int* __restrict__ dst,
                       int* __restrict__ bucket_cnt, unsigned int* __restrict__ binned,
                       int E, int NB) {
    __shared__ int hist[256];
    __shared__ int cur[256];
    int t = threadIdx.x;
    if (t < NB) hist[t] = 0;
    __syncthreads();
    int chunk = (E + gridDim.x - 1) / gridDim.x;
    int e0 = blockIdx.x * chunk;
    int e1 = min(E, e0 + chunk);
    for (int e = e0 + t; e < e1; e += THREADS) atomicAdd(&hist[dst[e] >> BKT_SHIFT], 1);
    __syncthreads();
    if (t < NB) {
        int c = hist[t];
        cur[t] = c ? atomicAdd(&bucket_cnt[t], c) : 0;
    }
    __syncthreads();
    for (int e = e0 + t; e < e1; e += THREADS) {
        int d = dst[e];
        int b = d >> BKT_SHIFT;
        int pos = atomicAdd(&cur[b], 1);
        if (pos < BKT_CAP)
            binned[(size_t)b * BKT_CAP + pos] =
                (unsigned int)src[e] | ((unsigned int)(d & (BKT_NODES - 1)) << 17);
    }
}

// ---------- scan bucket counts -> exclusive bucket_base; row_ptr[N]=E ----------
__global__ void k_scanB(const int* __restrict__ bucket_cnt, int* __restrict__ bucket_base,
                        int* __restrict__ row_ptr, int NB, int N, int E) {
    __shared__ int sh[1024];
    int t = threadIdx.x;
    int v = (t < NB) ? bucket_cnt[t] : 0;
    sh[t] = v;
    __syncthreads();
    for (int off = 1; off < 1024; off <<= 1) {
        int u = (t >= off) ? sh[t - off] : 0;
        __syncthreads();
        sh[t] += u;
        __syncthreads();
    }
    if (t < NB) bucket_base[t] = sh[t] - v;
    if (t == 0) row_ptr[N] = E;
}

// ---------- Pass B: per-bucket LDS hist+scan -> row_ptr, dinv, xs, esrc ----------
// esrc entries are PRE-SCALED to fp16-row byte offsets (node << 7)
__global__ void k_binB(const unsigned int* __restrict__ binned, const int* __restrict__ bucket_cnt,
                       const int* __restrict__ bucket_base, const float2* __restrict__ x,
                       int* __restrict__ row_ptr, float* __restrict__ dinv,
                       float2* __restrict__ xs, int* __restrict__ esrc, int N) {
    __shared__ int h[BKT_NODES], sc[BKT_NODES], cur[BKT_NODES];
    int b = blockIdx.x, t = threadIdx.x;   // blockDim = 512
    int cntb = min(bucket_cnt[b], BKT_CAP);
    int base = bucket_base[b];
    h[t] = 0;
    __syncthreads();
    const unsigned int* bp = binned + (size_t)b * BKT_CAP;
    for (int e = t; e < cntb; e += BKT_NODES) atomicAdd(&h[bp[e] >> 17], 1);
    __syncthreads();
    sc[t] = h[t];
    __syncthreads();
    for (int off = 1; off < BKT_NODES; off <<= 1) {
        int u = (t >= off) ? sc[t - off] : 0;
        __syncthreads();
        sc[t] += u;
        __syncthreads();
    }
    int node = b * BKT_NODES + t;
    if (node < N) {
        int excl = sc[t] - h[t];
        row_ptr[node] = base + excl;
        cur[t] = excl;
        float dv = rsqrtf((float)(h[t] + 1));
        dinv[node] = dv;
        float2 v = x[node];
        xs[node] = make_float2(v.x * dv, v.y * dv);
    }
    __syncthreads();
    for (int e = t; e < cntb; e += BKT_NODES) {
        unsigned int p = bp[e];
        int pos = atomicAdd(&cur[p >> 17], 1);
        esrc[base + pos] = (int)((p & 0x1FFFFu) << 7);
    }
}

// ---------- fused: 2-dim gather + layer-1 transform + layer-2 transform ----------
// 4 rows per wave in 16-lane groups for the gather (4-round shared reduce);
// matvec: lane j holds fp16 W2 column j (32 half2), two rows interleaved,
// h-pairs broadcast via v_readlane (no LDS).
__global__ void k_g2l12(const int* __restrict__ row_ptr, const int* __restrict__ esrc,
                        const float* __restrict__ dinv, const float2* __restrict__ xs,
                        const float* __restrict__ W1, const float* __restrict__ b1,
                        const float* __restrict__ W2, __half* __restrict__ A, int n) {
    int tid = threadIdx.x;
    int j = tid & 63;
    int gw = blockIdx.x * (THREADS / 64) + (tid >> 6);   // global wave id
    int row0 = gw * RPW;
    if (row0 >= n) return;

    h2 w2p[32];
#pragma unroll
    for (int m = 0; m < 32; ++m) {
        h2 w;
        w[0] = (_Float16)W2[(2 * m) * 64 + j];
        w[1] = (_Float16)W2[(2 * m + 1) * 64 + j];
        w2p[m] = w;
    }
    // lane m<32 owns h-columns 2m, 2m+1 (lanes >=32 duplicate lane 0's, unused)
    int jj = (j < 32) ? j : 0;
    float w1xa = W1[2 * jj],     w1ya = W1[64 + 2 * jj],     b1a = b1[2 * jj];
    float w1xb = W1[2 * jj + 1], w1yb = W1[64 + 2 * jj + 1], b1b = b1[2 * jj + 1];

    int r = j >> 4;          // row slot 0..3
    int u = j & 15;          // edge lane within group

    for (int g = 0; g < RPW; g += 4) {
        int rowg = row0 + g;
        int myrow = rowg + r;
        float ax = 0.0f, ay = 0.0f;
        if (myrow < n) {
            int e0 = row_ptr[myrow], e1 = row_ptr[myrow + 1];
            for (int e = e0 + u; e < e1; e += 16) {
                float2 v = xs[(unsigned)esrc[e] >> 7];
                ax += v.x;
                ay += v.y;
            }
        }
#pragma unroll
        for (int m = 1; m < 16; m <<= 1) {
            ax += __shfl_xor(ax, m, 64);
            ay += __shfl_xor(ay, m, 64);
        }
#pragma unroll
        for (int pr = 0; pr < 2; ++pr) {
            int rowA = rowg + 2 * pr;
            int rowB = rowA + 1;
            int rA = min(rowA, n - 1), rB = min(rowB, n - 1);
            float sxA = rdlane_f(ax, 32 * pr),      syA = rdlane_f(ay, 32 * pr);
            float sxB = rdlane_f(ax, 32 * pr + 16), syB = rdlane_f(ay, 32 * pr + 16);
            float2 ownA = xs[rA], ownB = xs[rB];
            float dvA = dinv[rA], dvB = dinv[rB];
            float gxA = (sxA + ownA.x) * dvA, gyA = (syA + ownA.y) * dvA;
            float gxB = (sxB + ownB.x) * dvB, gyB = (syB + ownB.y) * dvB;
            float haA = fmaxf(gxA * w1xa + gyA * w1ya + b1a, 0.0f);
            float hbA = fmaxf(gxA * w1xb + gyA * w1yb + b1b, 0.0f);
            float haB = fmaxf(gxB * w1xa + gyB * w1ya + b1a, 0.0f);
            float hbB = fmaxf(gxB * w1xb + gyB * w1yb + b1b, 0.0f);
            h2 pkA, pkB;
            pkA[0] = (_Float16)haA; pkA[1] = (_Float16)hbA;
            pkB[0] = (_Float16)haB; pkB[1] = (_Float16)hbB;
            unsigned hpuA = h2u(pkA), hpuB = h2u(pkB);
            float a0 = 0.f, a1 = 0.f, a2 = 0.f, a3 = 0.f;
            float c0 = 0.f, c1 = 0.f, c2 = 0.f, c3 = 0.f;
#pragma unroll
            for (int m = 0; m < 32; m += 4) {
                unsigned pA0 = (unsigned)__builtin_amdgcn_readlane((int)hpuA, m);
                unsigned pA1 = (unsigned)__builtin_amdgcn_readlane((int)hpuA, m + 1);
                unsigned pA2 = (unsigned)__builtin_amdgcn_readlane((int)hpuA, m + 2);
                unsigned pA3 = (unsigned)__builtin_amdgcn_readlane((int)hpuA, m + 3);
                unsigned pB0 = (unsigned)__builtin_amdgcn_readlane((int)hpuB, m);
                unsigned pB1 = (unsigned)__builtin_amdgcn_readlane((int)hpuB, m + 1);
                unsigned pB2 = (unsigned)__builtin_amdgcn_readlane((int)hpuB, m + 2);
                unsigned pB3 = (unsigned)__builtin_amdgcn_readlane((int)hpuB, m + 3);
                a0 = fdot2f(u2h(pA0), w2p[m], a0);
                a1 = fdot2f(u2h(pA1), w2p[m + 1], a1);
                a2 = fdot2f(u2h(pA2), w2p[m + 2], a2);
                a3 = fdot2f(u2h(pA3), w2p[m + 3], a3);
                c0 = fdot2f(u2h(pB0), w2p[m], c0);
                c1 = fdot2f(u2h(pB1), w2p[m + 1], c1);
                c2 = fdot2f(u2h(pB2), w2p[m + 2], c2);
                c3 = fdot2f(u2h(pB3), w2p[m + 3], c3);
            }
            float rAA = ((a0 + a1) + (a2 + a3)) * dvA;
            float rBB = ((c0 + c1) + (c2 + c3)) * dvB;
            float rAp = __shfl_xor(rAA, 1, 64);
            float rBp = __shfl_xor(rBB, 1, 64);
            if ((j & 1) == 0) {
                if (rowA < n) *(__half2*)&A[(size_t)rowA * 64 + j] = __floats2half2_rn(rAA, rAp);
                if (rowB < n) *(__half2*)&A[(size_t)rowB * 64 + j] = __floats2half2_rn(rBB, rBp);
            }
        }
    }
}

// unpack-accumulate 8 halves (one uint4) with v_dot2_f32_f16 (1 VALU op per dim)
__device__ inline void add8d(float a[8], uint4 u, h2 c10, h2 c01) {
    h2 p0 = u2h(u.x), p1 = u2h(u.y), p2 = u2h(u.z), p3 = u2h(u.w);
    a[0] = fdot2f(p0, c10, a[0]); a[1] = fdot2f(p0, c01, a[1]);
    a[2] = fdot2f(p1, c10, a[2]); a[3] = fdot2f(p1, c01, a[3]);
    a[4] = fdot2f(p2, c10, a[4]); a[5] = fdot2f(p2, c01, a[5]);
    a[6] = fdot2f(p3, c10, a[6]); a[7] = fdot2f(p3, c01, a[7]);
}

// ---------- fused: 64-dim fp16 aggregation + bias + relu + layer-3 transform ----------
// 4 nodes per wave; 16-lane group per node = 2 edge-slots x 8 dim-octets;
// each lane loads 16B = 8 halves; esrc holds row byte-offsets
__global__ void k_gather64f(const int* __restrict__ row_ptr, const int* __restrict__ esrc,
                            const float* __restrict__ dinv, const __half* __restrict__ tt,
                            const float* __restrict__ b2, const float* __restrict__ W3,
                            float* __restrict__ tt3, int n) {
    int tid = blockIdx.x * blockDim.x + threadIdx.x;
    int i = tid >> 4;               // node per 16-lane group
    if (i >= n) return;
    int lane = tid & 15;
    int q = lane >> 3;              // edge slot 0..1
    int c = lane & 7;               // dim octet 0..7 (dims 8c..8c+7)
    h2 c10, c01;
    c10[0] = (_Float16)1.0f; c10[1] = (_Float16)0.0f;
    c01[0] = (_Float16)0.0f; c01[1] = (_Float16)1.0f;
    const char* ttb = (const char*)tt + c * 16;
    float a[8];
#pragma unroll
    for (int d = 0; d < 8; ++d) a[d] = 0.0f;
    if (q == 0) add8d(a, *(const uint4*)(ttb + (size_t)i * 128), c10, c01);
    int e0 = row_ptr[i], e1 = row_ptr[i + 1];
    int e = e0 + q;
    for (; e + 6 < e1; e += 8) {
        unsigned o0 = (unsigned)esrc[e],     o1 = (unsigned)esrc[e + 2];
        unsigned o2 = (unsigned)esrc[e + 4], o3 = (unsigned)esrc[e + 6];
        uint4 u0 = *(const uint4*)(ttb + o0);
        uint4 u1 = *(const uint4*)(ttb + o1);
        uint4 u2 = *(const uint4*)(ttb + o2);
        uint4 u3 = *(const uint4*)(ttb + o3);
        add8d(a, u0, c10, c01);
        add8d(a, u1, c10, c01);
        add8d(a, u2, c10, c01);
        add8d(a, u3, c10, c01);
    }
    for (; e < e1; e += 2) {
        uint4 u = *(const uint4*)(ttb + (unsigned)esrc[e]);
        add8d(a, u, c10, c01);
    }
    // reduce across the 2 edge slots (lanes differing by 8)
#pragma unroll
    for (int d = 0; d < 8; ++d) a[d] += __shfl_xor(a[d], 8, 64);
    if (q == 0) {
        float dv = dinv[i];
        const float4 blo = *(const float4*)&b2[c * 8];
        const float4 bhi = *(const float4*)&b2[c * 8 + 4];
        const float4 wlo = *(const float4*)&W3[c * 8];
        const float4 whi = *(const float4*)&W3[c * 8 + 4];
        float p = fmaxf(a[0] * dv + blo.x, 0.0f) * wlo.x
                + fmaxf(a[1] * dv + blo.y, 0.0f) * wlo.y
                + fmaxf(a[2] * dv + blo.z, 0.0f) * wlo.z
                + fmaxf(a[3] * dv + blo.w, 0.0f) * wlo.w
                + fmaxf(a[4] * dv + bhi.x, 0.0f) * whi.x
                + fmaxf(a[5] * dv + bhi.y, 0.0f) * whi.y
                + fmaxf(a[6] * dv + bhi.z, 0.0f) * whi.z
                + fmaxf(a[7] * dv + bhi.w, 0.0f) * whi.w;
        // reduce across the 8 octet lanes
        p += __shfl_xor(p, 1, 64);
        p += __shfl_xor(p, 2, 64);
        p += __shfl_xor(p, 4, 64);
        if (c == 0) tt3[i] = p * dv;
    }
}

// out[i] = dinv[i]*(tt3[i] + sum tt3[esrc>>7]) + b3
__global__ void k_gather1(const int* __restrict__ row_ptr, const int* __restrict__ esrc,
                          const float* __restrict__ dinv, const float* __restrict__ tt3,
                          const float* __restrict__ b3, float* __restrict__ out, int n) {
    int i = blockIdx.x * blockDim.x + threadIdx.x;
    if (i >= n) return;
    float acc = tt3[i];
    int e = row_ptr[i], e1 = row_ptr[i + 1];
    for (; e + 4 <= e1; e += 4) {
        acc += tt3[(unsigned)esrc[e] >> 7] + tt3[(unsigned)esrc[e + 1] >> 7]
             + tt3[(unsigned)esrc[e + 2] >> 7] + tt3[(unsigned)esrc[e + 3] >> 7];
    }
    for (; e < e1; ++e) acc += tt3[(unsigned)esrc[e] >> 7];
    out[i] = acc * dinv[i] + b3[0];
}

extern "C" void kernel_launch(void* const* d_in, const int* in_sizes, int n_in,
                              void* d_out, int out_size, void* d_ws, size_t ws_size,
                              hipStream_t stream) {
    const float* x  = (const float*)d_in[0];
    const int*   ei = (const int*)d_in[1];
    const float* W1 = (const float*)d_in[2];
    const float* b1 = (const float*)d_in[3];
    const float* W2 = (const float*)d_in[4];
    const float* b2 = (const float*)d_in[5];
    const float* W3 = (const float*)d_in[6];
    const float* b3 = (const float*)d_in[7];
    float* out = (float*)d_out;

    const int N = in_sizes[0] / 2;
    const int E = in_sizes[1] / 2;
    const int* src = ei;
    const int* dst = ei + E;
    const int NB = (N + BKT_NODES - 1) >> BKT_SHIFT;

    char* ws = (char*)d_ws;
    float* dinv = (float*)ws;                       // N
    size_t off = ((size_t)N * sizeof(float) + 255) & ~(size_t)255;
    float* Af = (float*)(ws + off);                 // N*64 floats reserved (binned aliases)
    __half* A = (__half*)Af;                        // used as N*64 halves
    float* tt3 = Af + (size_t)N * 64;               // N
    float2* xs = (float2*)(tt3 + N);                // N float2
    int* bucket_cnt = (int*)(xs + N);               // <=256
    int* bucket_base = bucket_cnt + 256;            // <=256
    int* row_ptr = bucket_base + 256;               // N+1
    int* esrc = row_ptr + N + 2;                    // E
    unsigned int* binned = (unsigned int*)Af;       // NB*BKT_CAP u32

    dim3 blk(THREADS);
    dim3 gN((N + THREADS - 1) / THREADS);
    dim3 gN16((int)(((long long)N * 16 + THREADS - 1) / THREADS));

    // CSR build (bucket sort)
    k_zero_int<<<dim3(1), blk, 0, stream>>>(bucket_cnt, 256);
    k_binA<<<dim3(512), blk, 0, stream>>>(src, dst, bucket_cnt, binned, E, NB);
    k_scanB<<<dim3(1), dim3(1024), 0, stream>>>(bucket_cnt, bucket_base, row_ptr, NB, N, E);
    k_binB<<<dim3(NB), dim3(BKT_NODES), 0, stream>>>(binned, bucket_cnt, bucket_base,
                                                     (const float2*)x, row_ptr, dinv, xs, esrc, N);

    // layer 1 propagate (2-dim) + transforms 1&2 fused (16-lane gather, 2-row matvec)
    {
        int waves = (N + RPW - 1) / RPW;
        int blocks = (waves + (THREADS / 64) - 1) / (THREADS / 64);
        k_g2l12<<<dim3(blocks), blk, 0, stream>>>(row_ptr, esrc, dinv, xs, W1, b1, W2, A, N);
    }

    // layer 2 aggregation + bias/relu + layer-3 transform fused (fp16 table, dot2)
    k_gather64f<<<gN16, blk, 0, stream>>>(row_ptr, esrc, dinv, A, b2, W3, tt3, N);

    // layer 3 propagate
    k_gather1<<<gN, blk, 0, stream>>>(row_ptr, esrc, dinv, tt3, b3, out, N);
}